// Round 10
// baseline (124.490 us; speedup 1.0000x reference)
//
#include <hip/hip_runtime.h>
#include <hip/hip_bf16.h>

// GroupDense via bf16 MFMA, operand-swapped (y^T = K^T x^T) register pipeline:
//   y[r, g*64+v] = relu( sum_u x[r, g*64+u] * K[g,u,v] )
// x: [16384, 4096] fp32, K: [64,64,64] fp32, out fp32 (absmax thr 4.9e-2).
//
// Operand swap: A := K^T fragment, B := x-row fragment (mirror layouts) ->
// C/D is row-major per lane: lane l, reg q holds y[row=l&15][16c+4*(l>>4)+q]
// -> one float4 store per col-tile.
// x: global->register, per-lane row (32B contiguous), DEPTH-3 pipeline
//    (4 slots x 16 VGPR in flight; r9's depth-2 at VGPR=52 showed the
//    compiler collapsed the lookahead -> deepen and let regalloc hold it).
// K[g]: once per block -> bf16 transposed KT[v][u], 8-chunk XOR swizzle;
//    A-frags = 8 conflict-free ds_read_b128. One barrier total.
// out: PLAIN float4 stores. r9 measured: nontemporal = +27MB write
//    amplification (295 vs 262.6MB exact) and no FETCH benefit. Removed.

typedef short bf16x8 __attribute__((ext_vector_type(8)));
typedef float f32x4 __attribute__((ext_vector_type(4)));

constexpr int C_DIM = 4096;
constexpr int NGROUP = 64;
constexpr int THREADS = 256;          // 4 waves
constexpr int NT = 8;                 // 16-row tiles per wave
constexpr int ROWS_PER_BLOCK = 4 * NT * 16;   // 512

union BF8 { bf16x8 v; __hip_bfloat162 h[4]; };

static __device__ inline bf16x8 pack8(const float4& a, const float4& b) {
    BF8 u;
    u.h[0] = __float22bfloat162_rn(float2{a.x, a.y});
    u.h[1] = __float22bfloat162_rn(float2{a.z, a.w});
    u.h[2] = __float22bfloat162_rn(float2{b.x, b.y});
    u.h[3] = __float22bfloat162_rn(float2{b.z, b.w});
    return u.v;
}

__global__ __launch_bounds__(THREADS, 3) void group_dense_kernel(
    const float* __restrict__ x,
    const float* __restrict__ k,
    float* __restrict__ out)
{
    __shared__ __hip_bfloat16 KT[64 * 64];   // 8 KiB, transposed + swizzled

    const int bid = blockIdx.x;
    const int g = bid & (NGROUP - 1);
    const int row0 = (bid >> 6) * ROWS_PER_BLOCK;
    const int tid = threadIdx.x;
    const int wave = tid >> 6;
    const int lane = tid & 63;
    const int lr = lane & 15;
    const int lk = lane >> 4;

    // ---- x/out base for this lane (row = row0 + wave*128 + t*16 + lr) ----
    const float* xp = x + (size_t)(row0 + wave * 128 + lr) * C_DIM + g * 64 + 8 * lk;
    float* op = out + (size_t)(row0 + wave * 128 + lr) * C_DIM + g * 64 + 4 * lk;

    float4 buf[4][4];   // 4 slots, all indices compile-time (rule #20)
#define LOADT(SLOT, T) do {                                                   \
    const float4* p_ = (const float4*)(xp + (size_t)(T) * 16 * C_DIM);        \
    buf[SLOT][0] = p_[0];  /* u: 8lk..+3   */                                 \
    buf[SLOT][1] = p_[1];  /* u: 8lk+4..+7 */                                 \
    buf[SLOT][2] = p_[8];  /* u: 32+8lk..  */                                 \
    buf[SLOT][3] = p_[9];                                                     \
} while (0)

    // ---- issue first three tiles' loads before the K prologue ----
    LOADT(0, 0);
    LOADT(1, 1);
    LOADT(2, 2);

    // ---- K[g] -> KT (bf16, transposed [v][u], 8-chunk XOR swizzle) ----
    {
        const int v = tid & 63;
        const int c0 = tid >> 6;             // 0..3
        #pragma unroll
        for (int cc = 0; cc < 2; ++cc) {
            const int c = c0 + cc * 4;       // u-chunk 0..7 (8 u's each)
            const float* kp = k + (size_t)g * 4096 + (size_t)(8 * c) * 64 + v;
            float t[8];
            #pragma unroll
            for (int j = 0; j < 8; ++j) t[j] = kp[j * 64];  // coalesced in v
            BF8 u;
            u.h[0] = __float22bfloat162_rn(float2{t[0], t[1]});
            u.h[1] = __float22bfloat162_rn(float2{t[2], t[3]});
            u.h[2] = __float22bfloat162_rn(float2{t[4], t[5]});
            u.h[3] = __float22bfloat162_rn(float2{t[6], t[7]});
            *reinterpret_cast<bf16x8*>(&KT[v * 64 + ((c ^ (v & 7)) * 8)]) = u.v;
        }
    }
    __syncthreads();   // only barrier in the kernel

    // ---- A fragments (K^T): lane l -> A[v=16c+lr][u=8lk+j+32h] ----
    bf16x8 Af[4][2];
    #pragma unroll
    for (int c = 0; c < 4; ++c) {
        #pragma unroll
        for (int h = 0; h < 2; ++h) {
            const int v = 16 * c + lr;
            const int cu = 4 * h + lk;
            Af[c][h] = *reinterpret_cast<const bf16x8*>(
                &KT[v * 64 + ((cu ^ (v & 7)) * 8)]);
        }
    }

    // ---- main loop: depth-3 register pipeline ----
    #pragma unroll
    for (int t = 0; t < NT; ++t) {
        if (t + 3 < NT) LOADT((t + 3) & 3, t + 3);
        __builtin_amdgcn_sched_barrier(0);

        const bf16x8 b0 = pack8(buf[t & 3][0], buf[t & 3][1]);  // u 0..31
        const bf16x8 b1 = pack8(buf[t & 3][2], buf[t & 3][3]);  // u 32..63

        f32x4 ac0 = {0.f, 0.f, 0.f, 0.f};
        f32x4 ac1 = ac0, ac2 = ac0, ac3 = ac0;
        // D = A*B = K^T * x^T : lane l, reg q -> y[row lr][16c + 4lk + q]
        ac0 = __builtin_amdgcn_mfma_f32_16x16x32_bf16(Af[0][0], b0, ac0, 0, 0, 0);
        ac1 = __builtin_amdgcn_mfma_f32_16x16x32_bf16(Af[1][0], b0, ac1, 0, 0, 0);
        ac2 = __builtin_amdgcn_mfma_f32_16x16x32_bf16(Af[2][0], b0, ac2, 0, 0, 0);
        ac3 = __builtin_amdgcn_mfma_f32_16x16x32_bf16(Af[3][0], b0, ac3, 0, 0, 0);
        ac0 = __builtin_amdgcn_mfma_f32_16x16x32_bf16(Af[0][1], b1, ac0, 0, 0, 0);
        ac1 = __builtin_amdgcn_mfma_f32_16x16x32_bf16(Af[1][1], b1, ac1, 0, 0, 0);
        ac2 = __builtin_amdgcn_mfma_f32_16x16x32_bf16(Af[2][1], b1, ac2, 0, 0, 0);
        ac3 = __builtin_amdgcn_mfma_f32_16x16x32_bf16(Af[3][1], b1, ac3, 0, 0, 0);

        // ---- ReLU + 4 plain float4 stores (row lr, cols 16c+4lk..) ----
        float* ob = op + (size_t)t * 16 * C_DIM;
        #pragma unroll
        for (int c = 0; c < 4; ++c) {
            const f32x4 a = (c == 0) ? ac0 : (c == 1) ? ac1 : (c == 2) ? ac2 : ac3;
            float4 o;
            o.x = fmaxf(a[0], 0.0f);
            o.y = fmaxf(a[1], 0.0f);
            o.z = fmaxf(a[2], 0.0f);
            o.w = fmaxf(a[3], 0.0f);
            *reinterpret_cast<float4*>(ob + 16 * c) = o;
        }
        __builtin_amdgcn_sched_barrier(0);
    }
#undef LOADT
}

extern "C" void kernel_launch(void* const* d_in, const int* in_sizes, int n_in,
                              void* d_out, int out_size, void* d_ws, size_t ws_size,
                              hipStream_t stream) {
    const float* x = (const float*)d_in[0];   // [16384, 4096]
    const float* k = (const float*)d_in[1];   // [64, 64, 64]
    float* out = (float*)d_out;

    const int rows_total = in_sizes[0] / C_DIM;                  // 16384
    const int grid = (rows_total / ROWS_PER_BLOCK) * NGROUP;     // 32*64 = 2048
    group_dense_kernel<<<grid, THREADS, 0, stream>>>(x, k, out);
}

// Round 11
// 107.440 us; speedup vs baseline: 1.1587x; 1.1587x over previous
//
#include <hip/hip_runtime.h>
#include <hip/hip_bf16.h>

// GroupDense via bf16 MFMA, operand-swapped (y^T = K^T x^T) register pipeline:
//   y[r, g*64+v] = relu( sum_u x[r, g*64+u] * K[g,u,v] )
// x: [16384, 4096] fp32, K: [64,64,64] fp32, out fp32 (absmax thr 4.9e-2).
//
// EXACTLY the r9 winner (106.5us: depth-2, 3 buf slots, nontemporal stores)
// with ONE change: NT 8 -> 16 (1024 rows/block, grid 1024 = 4 blocks/CU),
// halving K-prologue/dispatch overhead per byte moved. r10 taught: depth-3 /
// 4-slot variant regressed 17% -- do not touch the pipeline shape.
//
// Operand swap: A := K^T fragment, B := x-row fragment (mirror layouts) ->
// C/D row-major per lane: lane l, reg q -> y[row=l&15][16c+4*(l>>4)+q]
// -> one float4 store per col-tile; lanes lk=0..3 of a row complete a
// contiguous 64B block per instruction (full-line writes).
// x: global->register, per-lane row (16B chunks), depth-2 prefetch;
// K[g]: once per block -> bf16 transposed KT[v][u], 8-chunk XOR swizzle;
//    A-frags = 8 conflict-free ds_read_b128. One barrier total.

typedef short bf16x8 __attribute__((ext_vector_type(8)));
typedef float f32x4 __attribute__((ext_vector_type(4)));

constexpr int C_DIM = 4096;
constexpr int NGROUP = 64;
constexpr int THREADS = 256;          // 4 waves
constexpr int NT = 16;                // 16-row tiles per wave
constexpr int ROWS_PER_BLOCK = 4 * NT * 16;   // 1024

union BF8 { bf16x8 v; __hip_bfloat162 h[4]; };

static __device__ inline bf16x8 pack8(const float4& a, const float4& b) {
    BF8 u;
    u.h[0] = __float22bfloat162_rn(float2{a.x, a.y});
    u.h[1] = __float22bfloat162_rn(float2{a.z, a.w});
    u.h[2] = __float22bfloat162_rn(float2{b.x, b.y});
    u.h[3] = __float22bfloat162_rn(float2{b.z, b.w});
    return u.v;
}

__global__ __launch_bounds__(THREADS, 3) void group_dense_kernel(
    const float* __restrict__ x,
    const float* __restrict__ k,
    float* __restrict__ out)
{
    __shared__ __hip_bfloat16 KT[64 * 64];   // 8 KiB, transposed + swizzled

    const int bid = blockIdx.x;
    const int g = bid & (NGROUP - 1);
    const int row0 = (bid >> 6) * ROWS_PER_BLOCK;
    const int tid = threadIdx.x;
    const int wave = tid >> 6;
    const int lane = tid & 63;
    const int lr = lane & 15;
    const int lk = lane >> 4;

    // ---- x/out base for this lane (row = row0 + wave*(NT*16) + t*16 + lr) ----
    const float* xp = x + (size_t)(row0 + wave * (NT * 16) + lr) * C_DIM + g * 64 + 8 * lk;
    float* op = out + (size_t)(row0 + wave * (NT * 16) + lr) * C_DIM + g * 64 + 4 * lk;

    float4 buf[3][4];   // 3 slots, all indices compile-time (rule #20)
#define LOADT(SLOT, T) do {                                                   \
    const float4* p_ = (const float4*)(xp + (size_t)(T) * 16 * C_DIM);        \
    buf[SLOT][0] = p_[0];  /* u: 8lk..+3   */                                 \
    buf[SLOT][1] = p_[1];  /* u: 8lk+4..+7 */                                 \
    buf[SLOT][2] = p_[8];  /* u: 32+8lk..  */                                 \
    buf[SLOT][3] = p_[9];                                                     \
} while (0)

    // ---- issue first two tiles' loads before the K prologue ----
    LOADT(0, 0);
    LOADT(1, 1);

    // ---- K[g] -> KT (bf16, transposed [v][u], 8-chunk XOR swizzle) ----
    {
        const int v = tid & 63;
        const int c0 = tid >> 6;             // 0..3
        #pragma unroll
        for (int cc = 0; cc < 2; ++cc) {
            const int c = c0 + cc * 4;       // u-chunk 0..7 (8 u's each)
            const float* kp = k + (size_t)g * 4096 + (size_t)(8 * c) * 64 + v;
            float t[8];
            #pragma unroll
            for (int j = 0; j < 8; ++j) t[j] = kp[j * 64];  // coalesced in v
            BF8 u;
            u.h[0] = __float22bfloat162_rn(float2{t[0], t[1]});
            u.h[1] = __float22bfloat162_rn(float2{t[2], t[3]});
            u.h[2] = __float22bfloat162_rn(float2{t[4], t[5]});
            u.h[3] = __float22bfloat162_rn(float2{t[6], t[7]});
            *reinterpret_cast<bf16x8*>(&KT[v * 64 + ((c ^ (v & 7)) * 8)]) = u.v;
        }
    }
    __syncthreads();   // only barrier in the kernel

    // ---- A fragments (K^T): lane l -> A[v=16c+lr][u=8lk+j+32h] ----
    bf16x8 Af[4][2];
    #pragma unroll
    for (int c = 0; c < 4; ++c) {
        #pragma unroll
        for (int h = 0; h < 2; ++h) {
            const int v = 16 * c + lr;
            const int cu = 4 * h + lk;
            Af[c][h] = *reinterpret_cast<const bf16x8*>(
                &KT[v * 64 + ((cu ^ (v & 7)) * 8)]);
        }
    }

    // ---- main loop: depth-2 register pipeline (r9 shape, do not touch) ----
    #pragma unroll
    for (int t = 0; t < NT; ++t) {
        if (t + 2 < NT) LOADT((t + 2) % 3, t + 2);
        __builtin_amdgcn_sched_barrier(0);

        const bf16x8 b0 = pack8(buf[t % 3][0], buf[t % 3][1]);  // u 0..31
        const bf16x8 b1 = pack8(buf[t % 3][2], buf[t % 3][3]);  // u 32..63

        f32x4 ac0 = {0.f, 0.f, 0.f, 0.f};
        f32x4 ac1 = ac0, ac2 = ac0, ac3 = ac0;
        // D = A*B = K^T * x^T : lane l, reg q -> y[row lr][16c + 4lk + q]
        ac0 = __builtin_amdgcn_mfma_f32_16x16x32_bf16(Af[0][0], b0, ac0, 0, 0, 0);
        ac1 = __builtin_amdgcn_mfma_f32_16x16x32_bf16(Af[1][0], b0, ac1, 0, 0, 0);
        ac2 = __builtin_amdgcn_mfma_f32_16x16x32_bf16(Af[2][0], b0, ac2, 0, 0, 0);
        ac3 = __builtin_amdgcn_mfma_f32_16x16x32_bf16(Af[3][0], b0, ac3, 0, 0, 0);
        ac0 = __builtin_amdgcn_mfma_f32_16x16x32_bf16(Af[0][1], b1, ac0, 0, 0, 0);
        ac1 = __builtin_amdgcn_mfma_f32_16x16x32_bf16(Af[1][1], b1, ac1, 0, 0, 0);
        ac2 = __builtin_amdgcn_mfma_f32_16x16x32_bf16(Af[2][1], b1, ac2, 0, 0, 0);
        ac3 = __builtin_amdgcn_mfma_f32_16x16x32_bf16(Af[3][1], b1, ac3, 0, 0, 0);

        // ---- ReLU + 4 nontemporal f32x4 stores (row lr, cols 16c+4lk..) ----
        float* ob = op + (size_t)t * 16 * C_DIM;
        #pragma unroll
        for (int c = 0; c < 4; ++c) {
            const f32x4 a = (c == 0) ? ac0 : (c == 1) ? ac1 : (c == 2) ? ac2 : ac3;
            f32x4 o;
            o[0] = fmaxf(a[0], 0.0f);
            o[1] = fmaxf(a[1], 0.0f);
            o[2] = fmaxf(a[2], 0.0f);
            o[3] = fmaxf(a[3], 0.0f);
            __builtin_nontemporal_store(o, reinterpret_cast<f32x4*>(ob + 16 * c));
        }
        __builtin_amdgcn_sched_barrier(0);
    }
#undef LOADT
}

extern "C" void kernel_launch(void* const* d_in, const int* in_sizes, int n_in,
                              void* d_out, int out_size, void* d_ws, size_t ws_size,
                              hipStream_t stream) {
    const float* x = (const float*)d_in[0];   // [16384, 4096]
    const float* k = (const float*)d_in[1];   // [64, 64, 64]
    float* out = (float*)d_out;

    const int rows_total = in_sizes[0] / C_DIM;                  // 16384
    const int grid = (rows_total / ROWS_PER_BLOCK) * NGROUP;     // 16*64 = 1024
    group_dense_kernel<<<grid, THREADS, 0, stream>>>(x, k, out);
}